// Round 1
// baseline (573.335 us; speedup 1.0000x reference)
//
#include <hip/hip_runtime.h>
#include <hip/hip_bf16.h>

#define NROWS 8192
#define DIM   1024
#define THRESH 0.85f

typedef __attribute__((ext_vector_type(4))) float f32x4;
typedef __attribute__((ext_vector_type(8))) short bf16x8;

__device__ __forceinline__ short f2bf(float x) {
    union { float f; unsigned u; } c; c.f = x;
    unsigned r = c.u + 0x7FFFu + ((c.u >> 16) & 1u);
    return (short)(r >> 16);
}

__device__ __forceinline__ void async16(const void* g, void* l) {
    __builtin_amdgcn_global_load_lds(
        (const __attribute__((address_space(1))) void*)g,
        (__attribute__((address_space(3))) void*)l, 16, 0, 0);
}

// ---------------- elementwise / prep kernels ----------------

__global__ __launch_bounds__(256) void f32_to_bf16_k(const float* __restrict__ in,
                                                     short* __restrict__ out, int n) {
    int i = (blockIdx.x * 256 + threadIdx.x) * 4;
    if (i < n) {
        float4 v = *(const float4*)(in + i);
        short4 o;
        o.x = f2bf(v.x); o.y = f2bf(v.y); o.z = f2bf(v.z); o.w = f2bf(v.w);
        *(short4*)(out + i) = o;
    }
}

// out[n][k] = in[k][n], converted to bf16
__global__ __launch_bounds__(256) void transpose_to_bf16_k(const float* __restrict__ in,
                                                           short* __restrict__ out, int dim) {
    __shared__ float tile[32][33];
    int bx = blockIdx.x * 32, by = blockIdx.y * 32;
    int tx = threadIdx.x, ty = threadIdx.y;
    for (int r = ty; r < 32; r += 8) tile[r][tx] = in[(size_t)(by + r) * dim + bx + tx];
    __syncthreads();
    for (int r = ty; r < 32; r += 8) out[(size_t)(bx + r) * dim + by + tx] = f2bf(tile[tx][r]);
}

__global__ void zero_f32_k(float* p, int n) {
    int i = blockIdx.x * blockDim.x + threadIdx.x;
    if (i < n) p[i] = 0.f;
}

// per-row LayerNorm + exact GELU, fp32 in -> bf16 out. block=256, one row/block.
__global__ __launch_bounds__(256) void ln_gelu_k(const float* __restrict__ h,
                                                 const float* __restrict__ gamma,
                                                 const float* __restrict__ beta,
                                                 short* __restrict__ g) {
    int row = blockIdx.x, t = threadIdx.x;
    const float* x = h + (size_t)row * DIM;
    float lv[4], s = 0.f, ss = 0.f;
    #pragma unroll
    for (int i = 0; i < 4; i++) {
        float v = x[t + i * 256];
        lv[i] = v; s += v; ss += v * v;
    }
    #pragma unroll
    for (int o = 32; o; o >>= 1) { s += __shfl_down(s, o, 64); ss += __shfl_down(ss, o, 64); }
    __shared__ float red[8];
    if ((t & 63) == 0) { red[(t >> 6) * 2] = s; red[(t >> 6) * 2 + 1] = ss; }
    __syncthreads();
    s  = red[0] + red[2] + red[4] + red[6];
    ss = red[1] + red[3] + red[5] + red[7];
    float mu = s * (1.0f / DIM);
    float var = ss * (1.0f / DIM) - mu * mu;
    float rstd = rsqrtf(var + 1e-5f);
    short* go = g + (size_t)row * DIM;
    #pragma unroll
    for (int i = 0; i < 4; i++) {
        int c = t + i * 256;
        float v = (lv[i] - mu) * rstd * gamma[c] + beta[c];
        float ge = 0.5f * v * (1.0f + erff(v * 0.70710678118654752f));
        go[c] = f2bf(ge);
    }
}

// per-row L2 normalize, fp32 in -> bf16 out
__global__ __launch_bounds__(256) void rownorm_bf16_k(const float* __restrict__ enc,
                                                      short* __restrict__ out) {
    int row = blockIdx.x, t = threadIdx.x;
    const float* x = enc + (size_t)row * DIM;
    float lv[4], ss = 0.f;
    #pragma unroll
    for (int i = 0; i < 4; i++) {
        float v = x[t + i * 256];
        lv[i] = v; ss += v * v;
    }
    #pragma unroll
    for (int o = 32; o; o >>= 1) ss += __shfl_down(ss, o, 64);
    __shared__ float red[4];
    if ((t & 63) == 0) red[t >> 6] = ss;
    __syncthreads();
    ss = red[0] + red[1] + red[2] + red[3];
    float inv = 1.0f / fmaxf(sqrtf(ss), 1e-12f);
    short* go = out + (size_t)row * DIM;
    #pragma unroll
    for (int i = 0; i < 4; i++) go[t + i * 256] = f2bf(lv[i] * inv);
}

// ---------------- MFMA GEMM: C[M][Nmat] = A[M][K] * Bt[Nmat][K]^T (+bias) ----------------
// m97-style: 128x128 block tile, 4 waves of 64x64, 16x16x32 bf16 MFMA,
// global_load_lds width=16, 2-barrier K-loop.
__global__ __launch_bounds__(256) void gemm_bt_k(const short* __restrict__ A,
                                                 const short* __restrict__ Bt,
                                                 float* __restrict__ C,
                                                 const float* __restrict__ bias,
                                                 float* __restrict__ dup,
                                                 int M, int Nmat, int K) {
    __shared__ short smA[128 * 32];
    __shared__ short smB[128 * 32];
    const int t = threadIdx.x;
    const int tileN = blockIdx.x * 128;
    const int tileM = blockIdx.y * 128;
    const int wave = t >> 6;
    const int wm = wave >> 1, wn = wave & 1;
    const int l = t & 63;

    // staging: thread t loads 16B = 8 bf16; row = t/4, colgroup = t%4
    const int sr = t >> 2;
    const int cg = (t & 3) * 8;
    const size_t aOff = (size_t)(tileM + sr) * K + cg;
    const size_t bOff = (size_t)(tileN + sr) * K + cg;
    const int ldsOff = sr * 32 + cg;

    f32x4 acc[4][4];
    #pragma unroll
    for (int i = 0; i < 4; i++)
        #pragma unroll
        for (int j = 0; j < 4; j++) acc[i][j] = (f32x4){0.f, 0.f, 0.f, 0.f};

    const int aBase = (wm * 64 + (l & 15)) * 32 + (l >> 4) * 8;
    const int bBase = (wn * 64 + (l & 15)) * 32 + (l >> 4) * 8;

    for (int k0 = 0; k0 < K; k0 += 32) {
        __syncthreads();
        async16(A + aOff + k0,                   smA + ldsOff);
        async16(A + aOff + (size_t)64 * K + k0,  smA + ldsOff + 64 * 32);
        async16(Bt + bOff + k0,                  smB + ldsOff);
        async16(Bt + bOff + (size_t)64 * K + k0, smB + ldsOff + 64 * 32);
        __syncthreads();

        bf16x8 af[4], bfr[4];
        #pragma unroll
        for (int i = 0; i < 4; i++) af[i] = *(const bf16x8*)(smA + aBase + i * 16 * 32);
        #pragma unroll
        for (int j = 0; j < 4; j++) bfr[j] = *(const bf16x8*)(smB + bBase + j * 16 * 32);
        #pragma unroll
        for (int i = 0; i < 4; i++)
            #pragma unroll
            for (int j = 0; j < 4; j++)
                acc[i][j] = __builtin_amdgcn_mfma_f32_16x16x32_bf16(af[i], bfr[j], acc[i][j], 0, 0, 0);
    }

    // epilogue: C/D layout col=lane&15, row=(lane>>4)*4+reg
    const int orow0 = tileM + wm * 64 + (l >> 4) * 4;
    const int ocol0 = tileN + wn * 64 + (l & 15);
    #pragma unroll
    for (int j = 0; j < 4; j++) {
        const int col = ocol0 + j * 16;
        const float bj = bias ? bias[col] : 0.f;
        #pragma unroll
        for (int i = 0; i < 4; i++) {
            #pragma unroll
            for (int r = 0; r < 4; r++) {
                const int row = orow0 + i * 16 + r;
                float v = acc[i][j][r] + bj;
                C[(size_t)row * Nmat + col] = v;
                if (dup && v > THRESH && row < col) dup[col] = 1.0f;
            }
        }
    }
}

// ---------------- launch ----------------

extern "C" void kernel_launch(void* const* d_in, const int* in_sizes, int n_in,
                              void* d_out, int out_size, void* d_ws, size_t ws_size,
                              hipStream_t stream) {
    const float* summaries = (const float*)d_in[0];
    const float* W1    = (const float*)d_in[1];
    const float* b1    = (const float*)d_in[2];
    const float* gamma = (const float*)d_in[3];
    const float* beta  = (const float*)d_in[4];
    const float* W2    = (const float*)d_in[5];
    const float* b2    = (const float*)d_in[6];

    float* sim = (float*)d_out;
    float* dup = sim + (size_t)NROWS * NROWS;

    char* ws = (char*)d_ws;
    float* hbuf = (float*)ws;                              // 32 MB: h, then enc
    short* xb   = (short*)(ws + (size_t)32 * 1024 * 1024); // 16 MB: Xb, then encb
    short* gbuf = (short*)(ws + (size_t)48 * 1024 * 1024); // 16 MB: g
    short* w1t  = (short*)(ws + (size_t)64 * 1024 * 1024); // 2 MB
    short* w2t  = (short*)(ws + (size_t)66 * 1024 * 1024); // 2 MB

    // prep
    f32_to_bf16_k<<<dim3(NROWS * DIM / 1024), dim3(256), 0, stream>>>(summaries, xb, NROWS * DIM);
    transpose_to_bf16_k<<<dim3(32, 32), dim3(32, 8), 0, stream>>>(W1, w1t, DIM);
    transpose_to_bf16_k<<<dim3(32, 32), dim3(32, 8), 0, stream>>>(W2, w2t, DIM);
    zero_f32_k<<<dim3(32), dim3(256), 0, stream>>>(dup, NROWS);

    // h = X @ W1 + b1
    gemm_bt_k<<<dim3(DIM / 128, NROWS / 128), dim3(256), 0, stream>>>(
        xb, w1t, hbuf, b1, (float*)nullptr, NROWS, DIM, DIM);
    // g = gelu(layernorm(h))
    ln_gelu_k<<<dim3(NROWS), dim3(256), 0, stream>>>(hbuf, gamma, beta, gbuf);
    // enc = g @ W2 + b2  (into hbuf)
    gemm_bt_k<<<dim3(DIM / 128, NROWS / 128), dim3(256), 0, stream>>>(
        gbuf, w2t, hbuf, b2, (float*)nullptr, NROWS, DIM, DIM);
    // encb = normalize(enc) in bf16 (into xb)
    rownorm_bf16_k<<<dim3(NROWS), dim3(256), 0, stream>>>(hbuf, xb);
    // sim = encb @ encb^T, fused duplicate detection
    gemm_bt_k<<<dim3(NROWS / 128, NROWS / 128), dim3(256), 0, stream>>>(
        xb, xb, sim, (const float*)nullptr, dup, NROWS, NROWS, DIM);
}

// Round 2
// 490.270 us; speedup vs baseline: 1.1694x; 1.1694x over previous
//
#include <hip/hip_runtime.h>
#include <hip/hip_bf16.h>

#define NROWS 8192
#define DIM   1024
#define THRESH 0.85f

typedef __attribute__((ext_vector_type(4))) float f32x4;
typedef __attribute__((ext_vector_type(8))) short bf16x8;

__device__ __forceinline__ short f2bf(float x) {
    union { float f; unsigned u; } c; c.f = x;
    unsigned r = c.u + 0x7FFFu + ((c.u >> 16) & 1u);
    return (short)(r >> 16);
}

__device__ __forceinline__ void async16(const void* g, void* l) {
    __builtin_amdgcn_global_load_lds(
        (const __attribute__((address_space(1))) void*)g,
        (__attribute__((address_space(3))) void*)l, 16, 0, 0);
}

// ---------------- elementwise / prep kernels ----------------

__global__ __launch_bounds__(256) void f32_to_bf16_k(const float* __restrict__ in,
                                                     short* __restrict__ out, int n) {
    int i = (blockIdx.x * 256 + threadIdx.x) * 4;
    if (i < n) {
        float4 v = *(const float4*)(in + i);
        short4 o;
        o.x = f2bf(v.x); o.y = f2bf(v.y); o.z = f2bf(v.z); o.w = f2bf(v.w);
        *(short4*)(out + i) = o;
    }
}

__global__ __launch_bounds__(256) void transpose_to_bf16_k(const float* __restrict__ in,
                                                           short* __restrict__ out, int dim) {
    __shared__ float tile[32][33];
    int bx = blockIdx.x * 32, by = blockIdx.y * 32;
    int tx = threadIdx.x, ty = threadIdx.y;
    for (int r = ty; r < 32; r += 8) tile[r][tx] = in[(size_t)(by + r) * dim + bx + tx];
    __syncthreads();
    for (int r = ty; r < 32; r += 8) out[(size_t)(bx + r) * dim + by + tx] = f2bf(tile[tx][r]);
}

__global__ void zero_f32_k(float* p, int n) {
    int i = blockIdx.x * blockDim.x + threadIdx.x;
    if (i < n) p[i] = 0.f;
}

__global__ __launch_bounds__(256) void ln_gelu_k(const float* __restrict__ h,
                                                 const float* __restrict__ gamma,
                                                 const float* __restrict__ beta,
                                                 short* __restrict__ g) {
    int row = blockIdx.x, t = threadIdx.x;
    const float* x = h + (size_t)row * DIM;
    float lv[4], s = 0.f, ss = 0.f;
    #pragma unroll
    for (int i = 0; i < 4; i++) {
        float v = x[t + i * 256];
        lv[i] = v; s += v; ss += v * v;
    }
    #pragma unroll
    for (int o = 32; o; o >>= 1) { s += __shfl_down(s, o, 64); ss += __shfl_down(ss, o, 64); }
    __shared__ float red[8];
    if ((t & 63) == 0) { red[(t >> 6) * 2] = s; red[(t >> 6) * 2 + 1] = ss; }
    __syncthreads();
    s  = red[0] + red[2] + red[4] + red[6];
    ss = red[1] + red[3] + red[5] + red[7];
    float mu = s * (1.0f / DIM);
    float var = ss * (1.0f / DIM) - mu * mu;
    float rstd = rsqrtf(var + 1e-5f);
    short* go = g + (size_t)row * DIM;
    #pragma unroll
    for (int i = 0; i < 4; i++) {
        int c = t + i * 256;
        float v = (lv[i] - mu) * rstd * gamma[c] + beta[c];
        float ge = 0.5f * v * (1.0f + erff(v * 0.70710678118654752f));
        go[c] = f2bf(ge);
    }
}

__global__ __launch_bounds__(256) void rownorm_bf16_k(const float* __restrict__ enc,
                                                      short* __restrict__ out) {
    int row = blockIdx.x, t = threadIdx.x;
    const float* x = enc + (size_t)row * DIM;
    float lv[4], ss = 0.f;
    #pragma unroll
    for (int i = 0; i < 4; i++) {
        float v = x[t + i * 256];
        lv[i] = v; ss += v * v;
    }
    #pragma unroll
    for (int o = 32; o; o >>= 1) ss += __shfl_down(ss, o, 64);
    __shared__ float red[4];
    if ((t & 63) == 0) red[t >> 6] = ss;
    __syncthreads();
    ss = red[0] + red[1] + red[2] + red[3];
    float inv = 1.0f / fmaxf(sqrtf(ss), 1e-12f);
    short* go = out + (size_t)row * DIM;
    #pragma unroll
    for (int i = 0; i < 4; i++) go[t + i * 256] = f2bf(lv[i] * inv);
}

// ---------------- MFMA GEMM: C[M][Nmat] = A[M][K] * Bt[Nmat][K]^T (+bias) ----------------
// 128x128 tile, 4 waves, 16x16x32 bf16 MFMA, global_load_lds width=16.
// XOR-swizzled LDS (source-side) for conflict-free ds_read_b128.
// LDS-transpose epilogue with coalesced float4 stores.
// mode 0: dense grid (bx=N tile, by=M tile), bias add.
// mode 1: triangular grid (1D, upper blocks only), mirrored writes, dup detect.
__global__ __launch_bounds__(256) void gemm_bt_k(const short* __restrict__ A,
                                                 const short* __restrict__ Bt,
                                                 float* __restrict__ C,
                                                 const float* __restrict__ bias,
                                                 float* __restrict__ dup,
                                                 int M, int Nmat, int K, int mode) {
    __shared__ __align__(16) char smraw[17024]; // stage: 16384 B (A+B) | epi: 32*132*4 = 16896 B
    short* smA = (short*)smraw;
    short* smB = smA + 128 * 32;
    float* epi = (float*)smraw;

    int bm, bn;
    if (mode == 1) {
        const int NB = Nmat >> 7;
        int bid = blockIdx.x, r = 0, off = 0;
        while (off + (NB - r) <= bid) { off += NB - r; r++; }
        bm = r; bn = r + (bid - off);
    } else {
        bn = blockIdx.x; bm = blockIdx.y;
    }
    const int tileN = bn * 128;
    const int tileM = bm * 128;

    const int t = threadIdx.x;
    const int wave = t >> 6;
    const int wm = wave >> 1, wn = wave & 1;
    const int l = t & 63;

    // staging: thread t's data lands at LDS byte offset t*16 (wave-uniform base + lane*16).
    // XOR-swizzle the SOURCE kgroup so frag reads are conflict-free.
    const int sr = t >> 2;                                   // row 0..63 (per 64-row half)
    const int swr = (sr & 3) ^ ((sr >> 2) & 3);
    const int cg = (((t & 3) ^ swr) & 3) * 8;                // source k-offset (elements)
    const size_t aOff = (size_t)(tileM + sr) * K + cg;
    const size_t bOff = (size_t)(tileN + sr) * K + cg;
    const int ldsOff = t * 8;                                // shorts

    f32x4 acc[4][4];
    #pragma unroll
    for (int i = 0; i < 4; i++)
        #pragma unroll
        for (int j = 0; j < 4; j++) acc[i][j] = (f32x4){0.f, 0.f, 0.f, 0.f};

    // fragment read addresses (swizzled)
    const int lr = l & 15;
    const int lq = l >> 4;
    const int sw = (lr & 3) ^ ((lr >> 2) & 3);
    const int kg = (lq ^ sw) & 3;
    const int aBase = (wm * 64 + lr) * 32 + kg * 8;
    const int bBase = (wn * 64 + lr) * 32 + kg * 8;

    for (int k0 = 0; k0 < K; k0 += 32) {
        __syncthreads();
        async16(A + aOff + k0,                   smA + ldsOff);
        async16(A + aOff + (size_t)64 * K + k0,  smA + ldsOff + 64 * 32);
        async16(Bt + bOff + k0,                  smB + ldsOff);
        async16(Bt + bOff + (size_t)64 * K + k0, smB + ldsOff + 64 * 32);
        __syncthreads();

        bf16x8 af[4], bfr[4];
        #pragma unroll
        for (int i = 0; i < 4; i++) af[i] = *(const bf16x8*)(smA + aBase + i * 16 * 32);
        #pragma unroll
        for (int j = 0; j < 4; j++) bfr[j] = *(const bf16x8*)(smB + bBase + j * 16 * 32);
        #pragma unroll
        for (int i = 0; i < 4; i++)
            #pragma unroll
            for (int j = 0; j < 4; j++)
                acc[i][j] = __builtin_amdgcn_mfma_f32_16x16x32_bf16(af[i], bfr[j], acc[i][j], 0, 0, 0);
    }

    // ---- epilogue: normal orientation, 4 chunks of 32 rows x 128 cols ----
    for (int ch = 0; ch < 4; ch++) {
        __syncthreads();
        #pragma unroll
        for (int j = 0; j < 4; j++) {
            const int cl = wn * 64 + j * 16 + lr;
            const float bj = bias ? bias[tileN + cl] : 0.f;
            #pragma unroll
            for (int r = 0; r < 4; r++) {
                const int rl = wm * 16 + lq * 4 + r;
                epi[rl * 132 + cl] = acc[ch][j][r] + bj;
            }
        }
        __syncthreads();
        #pragma unroll
        for (int k = 0; k < 4; k++) {
            const int v = k * 256 + t;
            const int rl = v >> 5;
            const int c4 = (v & 31) * 4;
            float4 vec = *(float4*)&epi[rl * 132 + c4];
            const int grow = tileM + (rl < 16 ? ch * 16 + rl : 48 + ch * 16 + rl);
            const int gcol = tileN + c4;
            *(float4*)&C[(size_t)grow * Nmat + gcol] = vec;
            if (mode == 1) {
                if (vec.x > THRESH && grow < gcol)     dup[gcol]     = 1.f;
                if (vec.y > THRESH && grow < gcol + 1) dup[gcol + 1] = 1.f;
                if (vec.z > THRESH && grow < gcol + 2) dup[gcol + 2] = 1.f;
                if (vec.w > THRESH && grow < gcol + 3) dup[gcol + 3] = 1.f;
            }
        }
    }

    // ---- mirrored (transposed) writes for off-diagonal triangular blocks ----
    if (mode == 1 && bm != bn) {
        const int mr = wn * 16 + lr;       // local out-row (tile col)
        for (int ch = 0; ch < 4; ch++) {   // ch = j (col chunk -> out-row chunk)
            __syncthreads();
            #pragma unroll
            for (int i = 0; i < 4; i++) {
                #pragma unroll
                for (int r = 0; r < 4; r++) {
                    const int mc = wm * 64 + i * 16 + lq * 4 + r; // out-col (tile row)
                    epi[mr * 132 + mc] = acc[i][ch][r];
                }
            }
            __syncthreads();
            #pragma unroll
            for (int k = 0; k < 4; k++) {
                const int v = k * 256 + t;
                const int rl = v >> 5;
                const int c4 = (v & 31) * 4;
                float4 vec = *(float4*)&epi[rl * 132 + c4];
                const int orow = tileN + ch * 16 + (rl < 16 ? rl : 48 + rl);
                *(float4*)&C[(size_t)orow * Nmat + tileM + c4] = vec;
            }
        }
    }
}

// ---------------- launch ----------------

extern "C" void kernel_launch(void* const* d_in, const int* in_sizes, int n_in,
                              void* d_out, int out_size, void* d_ws, size_t ws_size,
                              hipStream_t stream) {
    const float* summaries = (const float*)d_in[0];
    const float* W1    = (const float*)d_in[1];
    const float* b1    = (const float*)d_in[2];
    const float* gamma = (const float*)d_in[3];
    const float* beta  = (const float*)d_in[4];
    const float* W2    = (const float*)d_in[5];
    const float* b2    = (const float*)d_in[6];

    float* sim = (float*)d_out;
    float* dup = sim + (size_t)NROWS * NROWS;

    char* ws = (char*)d_ws;
    float* hbuf = (float*)ws;                              // 32 MB: h, then enc
    short* xb   = (short*)(ws + (size_t)32 * 1024 * 1024); // 16 MB: Xb, then encb
    short* gbuf = (short*)(ws + (size_t)48 * 1024 * 1024); // 16 MB: g
    short* w1t  = (short*)(ws + (size_t)64 * 1024 * 1024); // 2 MB
    short* w2t  = (short*)(ws + (size_t)66 * 1024 * 1024); // 2 MB

    f32_to_bf16_k<<<dim3(NROWS * DIM / 1024), dim3(256), 0, stream>>>(summaries, xb, NROWS * DIM);
    transpose_to_bf16_k<<<dim3(32, 32), dim3(32, 8), 0, stream>>>(W1, w1t, DIM);
    transpose_to_bf16_k<<<dim3(32, 32), dim3(32, 8), 0, stream>>>(W2, w2t, DIM);
    zero_f32_k<<<dim3(32), dim3(256), 0, stream>>>(dup, NROWS);

    // h = X @ W1 + b1
    gemm_bt_k<<<dim3(DIM / 128, NROWS / 128), dim3(256), 0, stream>>>(
        xb, w1t, hbuf, b1, (float*)nullptr, NROWS, DIM, DIM, 0);
    // g = gelu(layernorm(h))
    ln_gelu_k<<<dim3(NROWS), dim3(256), 0, stream>>>(hbuf, gamma, beta, gbuf);
    // enc = g @ W2 + b2
    gemm_bt_k<<<dim3(DIM / 128, NROWS / 128), dim3(256), 0, stream>>>(
        gbuf, w2t, hbuf, b2, (float*)nullptr, NROWS, DIM, DIM, 0);
    // encb = normalize(enc) in bf16
    rownorm_bf16_k<<<dim3(NROWS), dim3(256), 0, stream>>>(hbuf, xb);
    // sim = encb @ encb^T (upper-triangle blocks, mirrored writes, fused dup)
    const int NB = NROWS / 128;
    gemm_bt_k<<<dim3(NB * (NB + 1) / 2), dim3(256), 0, stream>>>(
        xb, xb, sim, (const float*)nullptr, dup, NROWS, NROWS, DIM, 1);
}